// Round 2
// baseline (8948.108 us; speedup 1.0000x reference)
//
#include <hip/hip_runtime.h>

#define NCOMP 19
#define NB    4096
// hierarchy: 256 leaf chunks of 4 steps = 16 superchunks of 16 leaves
#define NSUP  16
#define NSC   16
#define LSC   4

// workspace layout in doubles
#define WSD_Q   0                         // 2*361 doubles, Q[sys][col*19+j] (col-major)
#define WSD_P   722                       // 2*361 doubles
#define WSD_E   1444                      // NB*2*NSUP*19 doubles
#define WSD_XS  (1444 + NB*2*NSUP*NCOMP)  // NB*2*NSUP*19 doubles
// total = 1444 + 2*2,490,368 doubles ~= 39.9 MB

// ---------------- fp32 RK4 (matches reference semantics) ----------------
__device__ __forceinline__ void derivf(const float* __restrict__ y, float a, float bin,
                                       float* __restrict__ k) {
#pragma unroll
  for (int j = 0; j < NCOMP; ++j) {
    float s = -2.0f * y[j];
    if (j > 0) s += y[j - 1];
    if (j < NCOMP - 1) s += y[j + 1];
    k[j] = a * s;
  }
  k[NCOMP - 1] += bin;
}

__device__ __forceinline__ void rk4f(float* __restrict__ x, float a, float bin) {
  const float h = 0.01f, h2 = 0.005f, h6 = 0.01f / 6.0f;
  float k[NCOMP], y[NCOMP], acc[NCOMP];
  derivf(x, a, bin, k);
#pragma unroll
  for (int j = 0; j < NCOMP; ++j) { acc[j] = k[j]; y[j] = fmaf(h2, k[j], x[j]); }
  derivf(y, a, bin, k);
#pragma unroll
  for (int j = 0; j < NCOMP; ++j) { acc[j] = fmaf(2.0f, k[j], acc[j]); y[j] = fmaf(h2, k[j], x[j]); }
  derivf(y, a, bin, k);
#pragma unroll
  for (int j = 0; j < NCOMP; ++j) { acc[j] = fmaf(2.0f, k[j], acc[j]); y[j] = fmaf(h, k[j], x[j]); }
  derivf(y, a, bin, k);
#pragma unroll
  for (int j = 0; j < NCOMP; ++j) x[j] = fmaf(h6, acc[j] + k[j], x[j]);
}

// ---------------- fp64 RK4 (float-rounded constants to mirror reference) ----------------
__device__ __forceinline__ void derivd(const double* __restrict__ y, double a,
                                       double* __restrict__ k) {
#pragma unroll
  for (int j = 0; j < NCOMP; ++j) {
    double s = -2.0 * y[j];
    if (j > 0) s += y[j - 1];
    if (j < NCOMP - 1) s += y[j + 1];
    k[j] = a * s;
  }
}

__device__ __forceinline__ void rk4d(double* __restrict__ x, double a) {
  const double h = (double)0.01f, h2 = (double)0.005f, h6 = (double)(float)(0.01 / 6.0);
  double k[NCOMP], y[NCOMP], acc[NCOMP];
  derivd(x, a, k);
#pragma unroll
  for (int j = 0; j < NCOMP; ++j) { acc[j] = k[j]; y[j] = fma(h2, k[j], x[j]); }
  derivd(y, a, k);
#pragma unroll
  for (int j = 0; j < NCOMP; ++j) { acc[j] = fma(2.0, k[j], acc[j]); y[j] = fma(h2, k[j], x[j]); }
  derivd(y, a, k);
#pragma unroll
  for (int j = 0; j < NCOMP; ++j) { acc[j] = fma(2.0, k[j], acc[j]); y[j] = fma(h, k[j], x[j]); }
  derivd(y, a, k);
#pragma unroll
  for (int j = 0; j < NCOMP; ++j) x[j] = fma(h6, acc[j] + k[j], x[j]);
}

// ---------------- k0: Q = M^4, P = Q^16 (fp64, basis propagation + squaring) ----------------
__global__ __launch_bounds__(768) void k0_mats(const float* __restrict__ An,
                                               const float* __restrict__ Ap,
                                               double* __restrict__ wsd) {
  __shared__ double cur[2 * 361];
  __shared__ double nxt[2 * 361];
  int t = threadIdx.x;
  double aa[2];
  aa[0] = (double)An[1];
  aa[1] = (double)Ap[1];
  if (t < 2 * NCOMP) {
    int sys = t / NCOMP, col = t % NCOMP;
    double x[NCOMP];
#pragma unroll
    for (int j = 0; j < NCOMP; ++j) x[j] = 0.0;
    x[col] = 1.0;
    for (int s = 0; s < LSC; ++s) rk4d(x, aa[sys]);
#pragma unroll
    for (int j = 0; j < NCOMP; ++j) cur[sys * 361 + col * NCOMP + j] = x[j];
  }
  __syncthreads();
  if (t < 722) wsd[WSD_Q + t] = cur[t];   // save Q
  for (int r = 0; r < 4; ++r) {           // Q^2, Q^4, Q^8, Q^16
    if (t < 722) {
      int sys = t / 361, e = t % 361, col = e / NCOMP, j = e % NCOMP;
      const double* M = cur + sys * 361;
      double s = 0.0;
#pragma unroll
      for (int m = 0; m < NCOMP; ++m) s = fma(M[m * NCOMP + j], M[col * NCOMP + m], s);
      nxt[t] = s;
    }
    __syncthreads();
    if (t < 722) cur[t] = nxt[t];
    __syncthreads();
  }
  if (t < 722) wsd[WSD_P + t] = cur[t];
}

// ---------------- k1: leaf driven responses + Horner combine -> superchunk responses e ----
__global__ __launch_bounds__(256) void k1_combine(const float* __restrict__ iseq,
                                                  const float* __restrict__ An,
                                                  const float* __restrict__ Bn,
                                                  const float* __restrict__ Ap,
                                                  const float* __restrict__ Bp,
                                                  const double* __restrict__ wsd,
                                                  double* __restrict__ wse) {
  __shared__ float dls[256 * 21];   // [leaf c][j], stride 21 breaks bank collisions
  __shared__ double Qs[361];
  int t = threadIdx.x;
  int b = blockIdx.x >> 1, sys = blockIdx.x & 1;
  float a  = sys ? Ap[1] : An[1];
  float bl = sys ? Bp[NCOMP - 1] : Bn[NCOMP - 1];
  for (int i = t; i < 361; i += 256) Qs[i] = wsd[WSD_Q + sys * 361 + i];

  float x[NCOMP];
#pragma unroll
  for (int j = 0; j < NCOMP; ++j) x[j] = 0.0f;
  const float4 iv = *reinterpret_cast<const float4*>(iseq + (size_t)b * 1024 + t * 4);
  rk4f(x, a, iv.x * bl); rk4f(x, a, iv.y * bl); rk4f(x, a, iv.z * bl); rk4f(x, a, iv.w * bl);
#pragma unroll
  for (int j = 0; j < NCOMP; ++j) dls[t * 21 + j] = x[j];
  __syncthreads();

  if (t < NSUP) {   // lane t = superchunk s: e_s = sum_{cc} Q^{15-cc} d_cc  (Horner, fp64)
    double acc[NCOMP];
#pragma unroll
    for (int j = 0; j < NCOMP; ++j) acc[j] = (double)dls[(t * NSC) * 21 + j];
    for (int cc = 1; cc < NSC; ++cc) {
      double tmp[NCOMP];
#pragma unroll
      for (int j = 0; j < NCOMP; ++j) tmp[j] = (double)dls[(t * NSC + cc) * 21 + j];
#pragma unroll
      for (int col = 0; col < NCOMP; ++col) {
        double xc = acc[col];
#pragma unroll
        for (int j = 0; j < NCOMP; ++j) tmp[j] = fma(xc, Qs[col * NCOMP + j], tmp[j]);
      }
#pragma unroll
      for (int j = 0; j < NCOMP; ++j) acc[j] = tmp[j];
    }
    double* e = wse + ((size_t)(b * 2 + sys) * NSUP + t) * NCOMP;
#pragma unroll
    for (int j = 0; j < NCOMP; ++j) e[j] = acc[j];
  }
}

// ---------------- k2: scan superchunks: XS[s] = x;  x = P x + e[s]  (fp64) --------------
__global__ __launch_bounds__(256) void k2_scan(const float* __restrict__ xin,
                                               const double* __restrict__ wsd,
                                               const double* __restrict__ wse,
                                               double* __restrict__ wxs) {
  __shared__ double Ps[361];
  int g = blockIdx.x * 256 + threadIdx.x;   // 0..8191
  int sys = g >> 12;                        // uniform per block
  int b = g & (NB - 1);
  for (int i = threadIdx.x; i < 361; i += 256) Ps[i] = wsd[WSD_P + sys * 361 + i];
  __syncthreads();
  double x[NCOMP];
#pragma unroll
  for (int j = 0; j < NCOMP; ++j) x[j] = (double)xin[(size_t)b * (2 * NCOMP) + sys * NCOMP + j];
  for (int s = 0; s < NSUP; ++s) {
    size_t idx = ((size_t)(b * 2 + sys) * NSUP + s) * NCOMP;
    double tmp[NCOMP];
#pragma unroll
    for (int j = 0; j < NCOMP; ++j) { wxs[idx + j] = x[j]; tmp[j] = wse[idx + j]; }
#pragma unroll
    for (int col = 0; col < NCOMP; ++col) {
      double xc = x[col];
#pragma unroll
      for (int j = 0; j < NCOMP; ++j) tmp[j] = fma(xc, Ps[col * NCOMP + j], tmp[j]);
    }
#pragma unroll
    for (int j = 0; j < NCOMP; ++j) x[j] = tmp[j];
  }
}

// ---------------- k3: recompute leaf d -> LDS, expand leaf starts in LDS, emit ----------
__global__ __launch_bounds__(256) void k3_emit(const float* __restrict__ iseq,
                                               const float* __restrict__ An,
                                               const float* __restrict__ Bn,
                                               const float* __restrict__ Ap,
                                               const float* __restrict__ Bp,
                                               const double* __restrict__ wsd,
                                               const double* __restrict__ wxs,
                                               float* __restrict__ out) {
  __shared__ float dls[256 * 21];   // d, then overwritten in-place with leaf starts X0
  __shared__ double Qs[361];
  int t = threadIdx.x;
  int b = blockIdx.x >> 1, sys = blockIdx.x & 1;
  float a  = sys ? Ap[1] : An[1];
  float bl = sys ? Bp[NCOMP - 1] : Bn[NCOMP - 1];
  for (int i = t; i < 361; i += 256) Qs[i] = wsd[WSD_Q + sys * 361 + i];

  float x[NCOMP];
#pragma unroll
  for (int j = 0; j < NCOMP; ++j) x[j] = 0.0f;
  const float4 iv = *reinterpret_cast<const float4*>(iseq + (size_t)b * 1024 + t * 4);
  rk4f(x, a, iv.x * bl); rk4f(x, a, iv.y * bl); rk4f(x, a, iv.z * bl); rk4f(x, a, iv.w * bl);
#pragma unroll
  for (int j = 0; j < NCOMP; ++j) dls[t * 21 + j] = x[j];
  __syncthreads();

  if (t < NSUP) {   // lane t = superchunk s: walk leaves, leave X0 in LDS
    double xd[NCOMP];
    const double* xs = wxs + ((size_t)(b * 2 + sys) * NSUP + t) * NCOMP;
#pragma unroll
    for (int j = 0; j < NCOMP; ++j) xd[j] = xs[j];
    for (int cc = 0; cc < NSC; ++cc) {
      int c = t * NSC + cc;
      float dv[NCOMP];
#pragma unroll
      for (int j = 0; j < NCOMP; ++j) { dv[j] = dls[c * 21 + j]; dls[c * 21 + j] = (float)xd[j]; }
      double tmp[NCOMP];
#pragma unroll
      for (int j = 0; j < NCOMP; ++j) tmp[j] = (double)dv[j];
#pragma unroll
      for (int col = 0; col < NCOMP; ++col) {
        double xc = xd[col];
#pragma unroll
        for (int j = 0; j < NCOMP; ++j) tmp[j] = fma(xc, Qs[col * NCOMP + j], tmp[j]);
      }
#pragma unroll
      for (int j = 0; j < NCOMP; ++j) xd[j] = tmp[j];
    }
  }
  __syncthreads();

  float xs[NCOMP];
#pragma unroll
  for (int j = 0; j < NCOMP; ++j) xs[j] = dls[t * 21 + j];
  float b0[NCOMP], b1[NCOMP], b2[NCOMP], b3[NCOMP];
  rk4f(xs, a, iv.x * bl);
#pragma unroll
  for (int j = 0; j < NCOMP; ++j) b0[j] = xs[j];
  rk4f(xs, a, iv.y * bl);
#pragma unroll
  for (int j = 0; j < NCOMP; ++j) b1[j] = xs[j];
  rk4f(xs, a, iv.z * bl);
#pragma unroll
  for (int j = 0; j < NCOMP; ++j) b2[j] = xs[j];
  rk4f(xs, a, iv.w * bl);
#pragma unroll
  for (int j = 0; j < NCOMP; ++j) b3[j] = xs[j];

  float* orow = out + ((size_t)b * (2 * NCOMP) + sys * NCOMP) * 1024 + t * 4;
#pragma unroll
  for (int j = 0; j < NCOMP; ++j) {
    *reinterpret_cast<float4*>(orow + (size_t)j * 1024) =
        make_float4(b0[j], b1[j], b2[j], b3[j]);
  }
}

extern "C" void kernel_launch(void* const* d_in, const int* in_sizes, int n_in,
                              void* d_out, int out_size, void* d_ws, size_t ws_size,
                              hipStream_t stream) {
  const float* x    = (const float*)d_in[0];
  const float* iseq = (const float*)d_in[1];
  const float* An   = (const float*)d_in[2];
  const float* Bn   = (const float*)d_in[3];
  const float* Ap   = (const float*)d_in[4];
  const float* Bp   = (const float*)d_in[5];
  double* wsd = (double*)d_ws;
  float* out  = (float*)d_out;

  k0_mats<<<1, 768, 0, stream>>>(An, Ap, wsd);
  k1_combine<<<NB * 2, 256, 0, stream>>>(iseq, An, Bn, Ap, Bp, wsd, wsd + WSD_E);
  k2_scan<<<32, 256, 0, stream>>>(x, wsd, wsd + WSD_E, wsd + WSD_XS);
  k3_emit<<<NB * 2, 256, 0, stream>>>(iseq, An, Bn, Ap, Bp, wsd, wsd + WSD_XS, out);
}

// Round 4
// 178.863 us; speedup vs baseline: 50.0277x; 50.0277x over previous
//
#include <hip/hip_runtime.h>

#define NCOMP 19
#define NB    4096
#define PI_F  3.14159265358979323846f

__device__ __forceinline__ void derivf(const float* __restrict__ y, float a, float bin,
                                       float* __restrict__ k) {
#pragma unroll
  for (int j = 0; j < NCOMP; ++j) {
    float s = -2.0f * y[j];
    if (j > 0) s += y[j - 1];
    if (j < NCOMP - 1) s += y[j + 1];
    k[j] = a * s;
  }
  k[NCOMP - 1] += bin;
}

__device__ __forceinline__ void rk4f(float* __restrict__ x, float a, float bin) {
  const float h = 0.01f, h2 = 0.005f, h6 = 0.01f / 6.0f;
  float k[NCOMP], y[NCOMP], acc[NCOMP];
  derivf(x, a, bin, k);
#pragma unroll
  for (int j = 0; j < NCOMP; ++j) { acc[j] = k[j]; y[j] = fmaf(h2, k[j], x[j]); }
  derivf(y, a, bin, k);
#pragma unroll
  for (int j = 0; j < NCOMP; ++j) { acc[j] = fmaf(2.0f, k[j], acc[j]); y[j] = fmaf(h2, k[j], x[j]); }
  derivf(y, a, bin, k);
#pragma unroll
  for (int j = 0; j < NCOMP; ++j) { acc[j] = fmaf(2.0f, k[j], acc[j]); y[j] = fmaf(h, k[j], x[j]); }
  derivf(y, a, bin, k);
#pragma unroll
  for (int j = 0; j < NCOMP; ++j) x[j] = fmaf(h6, acc[j] + k[j], x[j]);
}

__global__ __launch_bounds__(256) void spm_fused(
    const float* __restrict__ xin, const float* __restrict__ iseq,
    const float* __restrict__ An, const float* __restrict__ Bn,
    const float* __restrict__ Ap, const float* __restrict__ Bp,
    float* __restrict__ out)
{
  __shared__ __align__(16) float Vs[NCOMP][20];  // V[k][j] (V symmetric), row pad -> 16B rows
  __shared__ float xs0[NCOMP];
  __shared__ float4 mcv[NCOMP];                  // (gi, w*gi, log2 g, s0) per mode
  __shared__ float wtot[NCOMP][4];               // per-wave scan totals

  const int t = threadIdx.x;
  const int lane = t & 63, wid = t >> 6;
  const int b = blockIdx.x >> 1, sys = blockIdx.x & 1;
  const float alpha = sys ? Ap[1] : An[1];            // matA[0][1]*alpha = alpha
  const float ab    = sys ? Bp[NCOMP - 1] : Bn[NCOMP - 1];  // alpha*beta

  // analytic eigenvectors of tridiag(1,-2,1): V[j][k] = sin((j+1)(k+1)pi/20)/sqrt(10)
  for (int idx = t; idx < NCOMP * 20; idx += 256) {
    int k = idx / 20, j = idx % 20;
    int m = ((k + 1) * (j + 1)) % 40;              // exact integer arg reduction
    Vs[k][j] = (j < NCOMP) ? sinf((float)m * (PI_F / 20.0f)) * 0.31622776601683794f : 0.0f;
  }
  if (t < NCOMP) xs0[t] = xin[(size_t)b * (2 * NCOMP) + sys * NCOMP + t];
  __syncthreads();

  if (t < NCOMP) {
    float sk = sinf((float)(t + 1) * (PI_F / 40.0f));
    float z  = 0.01f * alpha * (-4.0f * sk * sk);   // h*alpha*lambda_k
    float g  = 1.0f + z * (1.0f + z * (0.5f + z * ((1.0f/6.0f) + z * (1.0f/24.0f))));
    float S  = 1.0f + z * (0.5f + z * ((1.0f/6.0f) + z * (1.0f/24.0f)));
    float gi = 1.0f / g;
    float s0 = 0.0f;
#pragma unroll
    for (int j = 0; j < NCOMP; ++j) s0 = fmaf(Vs[t][j], xs0[j], s0);
    mcv[t] = make_float4(gi, 0.01f * S * ab * Vs[t][NCOMP - 1] * gi, __builtin_log2f(g), s0);
  }
  __syncthreads();

  const float4 iv = *reinterpret_cast<const float4*>(iseq + (size_t)b * 1024 + t * 4);

  float x0[20];
#pragma unroll
  for (int j = 0; j < 20; ++j) x0[j] = 0.0f;

#pragma unroll
  for (int k = 0; k < NCOMP; ++k) {
    const float4 c = mcv[k];
    const float gi = c.x, wgi = c.y, lg = c.z, s0 = c.w;
    // r = sum_u g^{-u} i_u over this thread's 4 inputs (Horner)
    float r = iv.x + gi * (iv.y + gi * (iv.z + gi * iv.w));
    float e = (float)(4 * t) * lg;                 // log2(g^{4t})
    float a = __builtin_exp2f(-e) * r;             // g^{-4t} * r
    // wave-level inclusive scan
    float v = a;
#pragma unroll
    for (int d = 1; d < 64; d <<= 1) {
      float o = __shfl_up(v, d);
      if (lane >= d) v += o;
    }
    if (lane == 63) wtot[k][wid] = v;
    __syncthreads();
    float C = v - a;                               // exclusive within wave
#pragma unroll
    for (int ww = 0; ww < 3; ++ww)
      if (ww < wid) C += wtot[k][ww];              // cross-wave offset (wave-uniform)
    // s at leaf start: g^{4t} * (s0 + w*g^{-1}*C)
    float s = __builtin_exp2f(e) * fmaf(wgi, C, s0);
    // x0 += s * V[:,k]   (vectorized LDS reads, row padded to 20)
    const float4* vr = reinterpret_cast<const float4*>(&Vs[k][0]);
#pragma unroll
    for (int q = 0; q < 5; ++q) {
      float4 vv = vr[q];
      x0[4*q+0] = fmaf(s, vv.x, x0[4*q+0]);
      x0[4*q+1] = fmaf(s, vv.y, x0[4*q+1]);
      x0[4*q+2] = fmaf(s, vv.z, x0[4*q+2]);
      x0[4*q+3] = fmaf(s, vv.w, x0[4*q+3]);
    }
  }
  if (t == 0) {   // exact initial state at t=0 (no reconstruction error)
#pragma unroll
    for (int j = 0; j < NCOMP; ++j) x0[j] = xs0[j];
  }

  // 4 reference-identical RK4 steps; buffer then emit coalesced float4 per component
  float b0[NCOMP], b1[NCOMP], b2[NCOMP], b3[NCOMP];
  rk4f(x0, alpha, iv.x * ab);
#pragma unroll
  for (int j = 0; j < NCOMP; ++j) b0[j] = x0[j];
  rk4f(x0, alpha, iv.y * ab);
#pragma unroll
  for (int j = 0; j < NCOMP; ++j) b1[j] = x0[j];
  rk4f(x0, alpha, iv.z * ab);
#pragma unroll
  for (int j = 0; j < NCOMP; ++j) b2[j] = x0[j];
  rk4f(x0, alpha, iv.w * ab);
#pragma unroll
  for (int j = 0; j < NCOMP; ++j) b3[j] = x0[j];

  float* orow = out + ((size_t)b * (2 * NCOMP) + sys * NCOMP) * 1024 + t * 4;
#pragma unroll
  for (int j = 0; j < NCOMP; ++j) {
    *reinterpret_cast<float4*>(orow + (size_t)j * 1024) =
        make_float4(b0[j], b1[j], b2[j], b3[j]);
  }
}

extern "C" void kernel_launch(void* const* d_in, const int* in_sizes, int n_in,
                              void* d_out, int out_size, void* d_ws, size_t ws_size,
                              hipStream_t stream) {
  const float* x    = (const float*)d_in[0];
  const float* iseq = (const float*)d_in[1];
  const float* An   = (const float*)d_in[2];
  const float* Bn   = (const float*)d_in[3];
  const float* Ap   = (const float*)d_in[4];
  const float* Bp   = (const float*)d_in[5];
  float* out = (float*)d_out;

  spm_fused<<<NB * 2, 256, 0, stream>>>(x, iseq, An, Bn, Ap, Bp, out);
}